// Round 7
// baseline (83.509 us; speedup 1.0000x reference)
//
#include <hip/hip_runtime.h>
#include <hip/hip_bf16.h>
#include <stdint.h>

// RNDiscriminator: B=64, d^2=64 positions, 26 features, g: 52->256->256, f: 256->1
// h1[i,j] = relu(u'[j] + v[i]); dominant cost sum_ij relu(h1 @ W2 + b2) = 34.4 GF bf16.
//
// k3: Bf[8][4] W2 fragments resident in regs (static indices only -- rule #20).
// h1 double-buffered (2x32KB LDS). Stage of unit q+1 is CHUNKED and interleaved
// between the 8 ks-MFMA clusters of unit q (loads get an MFMA shadow).
// Staging VALU is packed f32 (v_pk_add_f32 via f32x2 vector ops) + ds_write_b128.
// b = blk&63 keeps the 8 blocks sharing a u-tile on one XCD (L2 reuse).

typedef float f32x4 __attribute__((ext_vector_type(4)));
typedef float f32x2 __attribute__((ext_vector_type(2)));
typedef short short8 __attribute__((ext_vector_type(8)));
typedef int   int4v  __attribute__((ext_vector_type(4)));

__device__ __forceinline__ uint32_t cvt_pk_bf16(float lo, float hi) {
    uint32_t r;
    asm("v_cvt_pk_bf16_f32 %0, %1, %2" : "=v"(r) : "v"(lo), "v"(hi));
    return r;
}
__device__ __forceinline__ f32x2 relu2(f32x2 a) {
    f32x2 z = (f32x2){0.f, 0.f};
    return __builtin_elementwise_max(a, z);
}

// K12: blocks 0..255: fused conv(8x8/s8)+relu+coords -> u,v rows.
//      blocks 256..287: pre-fragment W2 (bf16, fragment-major).
__global__ void k12_front(const float* __restrict__ img, const float* __restrict__ cw,
                          const float* __restrict__ cb, const float* __restrict__ w1,
                          const float* __restrict__ b1, const float* __restrict__ w2,
                          float* __restrict__ u, float* __restrict__ v,
                          short* __restrict__ w2f) {
    int g = blockIdx.x;
    int t = threadIdx.x;
    if (g >= 256) {
        int fi = (g - 256) * 4 + (t >> 6);
        int l = t & 63;
        int ks = fi >> 4, ni2 = fi & 15;
        int n  = ni2 * 16 + (l & 15);
        int k0 = ks * 32 + (l >> 4) * 8;
        float f[8];
        #pragma unroll
        for (int e = 0; e < 8; ++e) f[e] = w2[(k0 + e) * 256 + n];
        union { short8 s; uint32_t w[4]; } A;
        A.w[0] = cvt_pk_bf16(f[0], f[1]);
        A.w[1] = cvt_pk_bf16(f[2], f[3]);
        A.w[2] = cvt_pk_bf16(f[4], f[5]);
        A.w[3] = cvt_pk_bf16(f[6], f[7]);
        *(short8*)(w2f + (fi * 64 + l) * 8) = A.s;
        return;
    }
    __shared__ float xs[16][26];
    int b = g >> 2, q = g & 3, p0 = q * 16;

    for (int idx = t; idx < 416; idx += 256) {
        int pl = idx / 26;
        int ch = idx - pl * 26;
        int pos = p0 + pl;
        int r = pos >> 3, c = pos & 7;
        float val;
        if (ch < 24) {
            float s = cb[ch];
            #pragma unroll
            for (int ci = 0; ci < 3; ++ci)
                #pragma unroll
                for (int kr = 0; kr < 8; ++kr) {
                    const float* ip = img + ((b * 3 + ci) * 64 + r * 8 + kr) * 64 + c * 8;
                    const float* wp = cw + ((ch * 3 + ci) * 8 + kr) * 8;
                    #pragma unroll
                    for (int kc = 0; kc < 8; ++kc) s += ip[kc] * wp[kc];
                }
            val = fmaxf(s, 0.f);
        } else if (ch == 24) {
            val = -1.f + (2.f / 7.f) * (float)c;
        } else {
            val = -1.f + (2.f / 7.f) * (float)r;
        }
        xs[pl][ch] = val;
    }
    __syncthreads();

    int c = t;
    for (int r = 0; r < 16; ++r) {
        float su = b1[c], sv = 0.f;
        #pragma unroll
        for (int k = 0; k < 26; ++k) {
            float xv = xs[r][k];
            su += xv * w1[k * 256 + c];
            sv += xv * w1[(26 + k) * 256 + c];
        }
        int bj = b * 64 + p0 + r;
        u[bj * 256 + c] = su;
        v[bj * 256 + c] = sv;
    }
}

// ---- k3 helper macros ----
// Staging: thread (col16 = t&31, rowbase = t>>5); pass p covers row p*8+rowbase,
// bf16 elems col16*8..+8 -> one ds_write_b128 at byte
// row*512 + (col16*16 ^ (rowbase<<4)) (16B-slot XOR swizzle; rowbase = row&7).
#define ULOAD(P, X0, X1)                                          \
    { X0 = *(const f32x4*)(uth + (P) * 2048);                     \
      X1 = *(const f32x4*)(uth + (P) * 2048 + 4); }

#define CONSUME(P, X0, X1, VA, VB, WB)                            \
    { f32x2 a0 = relu2((f32x2){X0.x, X0.y} + (f32x2){VA.x, VA.y});\
      f32x2 a1 = relu2((f32x2){X0.z, X0.w} + (f32x2){VA.z, VA.w});\
      f32x2 a2 = relu2((f32x2){X1.x, X1.y} + (f32x2){VB.x, VB.y});\
      f32x2 a3 = relu2((f32x2){X1.z, X1.w} + (f32x2){VB.z, VB.w});\
      int4v d;                                                    \
      d.x = (int)cvt_pk_bf16(a0.x, a0.y);                         \
      d.y = (int)cvt_pk_bf16(a1.x, a1.y);                         \
      d.z = (int)cvt_pk_bf16(a2.x, a2.y);                         \
      d.w = (int)cvt_pk_bf16(a3.x, a3.y);                         \
      *(int4v*)((WB) + (P) * 4096) = d; }

// Read: A-frag (row = mi*16+lr, ks, lg) at byte
// mi*8192 + lr*512 + (ks>>1)*128 + (xb or xb^64), xb = (lg*16)^((lr&7)<<4).
#define MFMA_ROW(AV, MI, KS)                                                           \
      acc[MI][0] = __builtin_amdgcn_mfma_f32_16x16x32_bf16(AV, Bf[KS][0], acc[MI][0], 0, 0, 0); \
      acc[MI][1] = __builtin_amdgcn_mfma_f32_16x16x32_bf16(AV, Bf[KS][1], acc[MI][1], 0, 0, 0); \
      acc[MI][2] = __builtin_amdgcn_mfma_f32_16x16x32_bf16(AV, Bf[KS][2], acc[MI][2], 0, 0, 0); \
      acc[MI][3] = __builtin_amdgcn_mfma_f32_16x16x32_bf16(AV, Bf[KS][3], acc[MI][3], 0, 0, 0);

#define MFMA_KS(KS)                                                   \
    { const char* hx = ((KS) & 1) ? hO : hE;                          \
      short8 a0 = *(const short8*)(hx + ((KS) >> 1) * 128);           \
      short8 a1 = *(const short8*)(hx + 8192  + ((KS) >> 1) * 128);   \
      short8 a2 = *(const short8*)(hx + 16384 + ((KS) >> 1) * 128);   \
      short8 a3 = *(const short8*)(hx + 24576 + ((KS) >> 1) * 128);   \
      __builtin_amdgcn_s_setprio(1);                                  \
      MFMA_ROW(a0, 0, KS) MFMA_ROW(a1, 1, KS)                         \
      MFMA_ROW(a2, 2, KS) MFMA_ROW(a3, 3, KS)                         \
      __builtin_amdgcn_s_setprio(0); }

__global__ __launch_bounds__(256, 2) void k3_pairs(
        const float* __restrict__ u, const float* __restrict__ v,
        const short* __restrict__ w2f, const float* __restrict__ b2,
        float* __restrict__ part) {
    __shared__ short h1s[2][64 * 256];   // 2 x 32 KB
    int t = threadIdx.x;
    int lane = t & 63, wv = t >> 6;
    int lr = lane & 15, lg = lane >> 4;
    int blk = blockIdx.x;                 // 0..511
    int b = blk & 63, i0 = (blk >> 6) * 8;

    // resident B fragments (static indices only)
    short8 Bf[8][4];
    #pragma unroll
    for (int ks = 0; ks < 8; ++ks)
        #pragma unroll
        for (int cg = 0; cg < 4; ++cg)
            Bf[ks][cg] = *(const short8*)(w2f + ((ks * 16 + wv * 4 + cg) * 64 + lane) * 8);

    f32x2 bias2[4];
    #pragma unroll
    for (int cg = 0; cg < 4; ++cg) {
        float bv = b2[wv * 64 + cg * 16 + lr];
        bias2[cg] = (f32x2){bv, bv};
    }

    // staging geometry
    int col16 = t & 31, rowbase = t >> 5;
    const float* uth = u + (b * 64 + rowbase) * 256 + col16 * 8;
    const float* vth = v + (b * 64 + i0) * 256 + col16 * 8;
    int wbase = rowbase * 512 + ((col16 * 16) ^ (rowbase << 4));

    // read geometry
    int xb = (lg * 16) ^ ((lr & 7) << 4);
    int rE = lr * 512 + xb;
    int rO = lr * 512 + (xb ^ 64);

    // ---- prologue: stage unit 0 into buf 0 ----
    {
        f32x4 va = *(const f32x4*)(vth);
        f32x4 vb = *(const f32x4*)(vth + 4);
        char* wb0 = (char*)h1s[0] + wbase;
        f32x4 x0, x1;
        #pragma unroll
        for (int p = 0; p < 8; ++p) {
            ULOAD(p, x0, x1)
            CONSUME(p, x0, x1, va, vb, wb0)
        }
    }
    __syncthreads();

    f32x2 csum2[4];
    #pragma unroll
    for (int cg = 0; cg < 4; ++cg) csum2[cg] = (f32x2){0.f, 0.f};
    const float* vnp = vth + 256;    // v row for unit 1

    #pragma unroll 1
    for (int qq = 0; qq < 8; ++qq) {
        const char* hE = (const char*)h1s[qq & 1] + rE;
        const char* hO = (const char*)h1s[qq & 1] + rO;
        char* wb = (char*)h1s[(qq & 1) ^ 1] + wbase;
        bool pre = (qq < 7);

        f32x4 acc[4][4];
        #pragma unroll
        for (int mi = 0; mi < 4; ++mi)
            #pragma unroll
            for (int cg = 0; cg < 4; ++cg) acc[mi][cg] = (f32x4){0.f, 0.f, 0.f, 0.f};

        f32x4 va, vb, x0, x1, y0, y1;
        if (pre) { va = *(const f32x4*)vnp; vb = *(const f32x4*)(vnp + 4); ULOAD(0, x0, x1) }
        MFMA_KS(0)
        if (pre) { ULOAD(1, y0, y1) CONSUME(0, x0, x1, va, vb, wb) }
        MFMA_KS(1)
        if (pre) { ULOAD(2, x0, x1) CONSUME(1, y0, y1, va, vb, wb) }
        MFMA_KS(2)
        if (pre) { ULOAD(3, y0, y1) CONSUME(2, x0, x1, va, vb, wb) }
        MFMA_KS(3)
        if (pre) { ULOAD(4, x0, x1) CONSUME(3, y0, y1, va, vb, wb) }
        MFMA_KS(4)
        if (pre) { ULOAD(5, y0, y1) CONSUME(4, x0, x1, va, vb, wb) }
        MFMA_KS(5)
        if (pre) { ULOAD(6, x0, x1) CONSUME(5, y0, y1, va, vb, wb) }
        MFMA_KS(6)
        if (pre) { ULOAD(7, y0, y1) CONSUME(6, x0, x1, va, vb, wb) }
        MFMA_KS(7)
        if (pre) { CONSUME(7, y0, y1, va, vb, wb) }

        // epilogue: relu(C + b2) partial column-sum (packed)
        #pragma unroll
        for (int cg = 0; cg < 4; ++cg) {
            #pragma unroll
            for (int mi = 0; mi < 4; ++mi) {
                f32x2 lo = relu2((f32x2){acc[mi][cg].x, acc[mi][cg].y} + bias2[cg]);
                f32x2 hi = relu2((f32x2){acc[mi][cg].z, acc[mi][cg].w} + bias2[cg]);
                csum2[cg] = csum2[cg] + lo + hi;
            }
        }
        __syncthreads();
        vnp += 256;
    }

    // flush: reduce over lg groups; lanes 0-15 store
    #pragma unroll
    for (int cg = 0; cg < 4; ++cg) {
        float s = csum2[cg].x + csum2[cg].y;
        s += __shfl_xor(s, 16);
        s += __shfl_xor(s, 32);
        if (lane < 16) part[blk * 256 + wv * 64 + cg * 16 + lr] = s;
    }
}

// K5: pooled[b] = sum of the 8 part rows for b (blk = b + 64*g); then f-head.
__global__ void k5_head(const float* __restrict__ part, const float* __restrict__ fw1,
                        const float* __restrict__ fb1, const float* __restrict__ fw2,
                        const float* __restrict__ fb2, float* __restrict__ out) {
    __shared__ float P[256];
    __shared__ float wsum[4];
    int b = blockIdx.x, t = threadIdx.x;
    float s0 = 0.f;
    #pragma unroll
    for (int g = 0; g < 8; ++g) s0 += part[(b + 64 * g) * 256 + t];
    P[t] = s0;
    __syncthreads();
    float a0 = 0.f, a1 = 0.f, a2 = 0.f, a3 = 0.f;
    for (int k = 0; k < 64; ++k) {
        a0 += P[k]       * fw1[k * 256 + t];
        a1 += P[k + 64]  * fw1[(k + 64) * 256 + t];
        a2 += P[k + 128] * fw1[(k + 128) * 256 + t];
        a3 += P[k + 192] * fw1[(k + 192) * 256 + t];
    }
    float h = fmaxf(fb1[t] + a0 + a1 + a2 + a3, 0.f);
    float p = h * fw2[t];
    #pragma unroll
    for (int off = 32; off >= 1; off >>= 1) p += __shfl_xor(p, off);
    if ((t & 63) == 0) wsum[t >> 6] = p;
    __syncthreads();
    if (t == 0) out[b] = wsum[0] + wsum[1] + wsum[2] + wsum[3] + fb2[0];
}

extern "C" void kernel_launch(void* const* d_in, const int* in_sizes, int n_in,
                              void* d_out, int out_size, void* d_ws, size_t ws_size,
                              hipStream_t stream) {
    const float* image  = (const float*)d_in[0];
    const float* conv_w = (const float*)d_in[1];
    const float* conv_b = (const float*)d_in[2];
    const float* g_w1   = (const float*)d_in[3];
    const float* g_b1   = (const float*)d_in[4];
    const float* g_w2   = (const float*)d_in[5];
    const float* g_b2   = (const float*)d_in[6];
    const float* f_w1   = (const float*)d_in[7];
    const float* f_b1   = (const float*)d_in[8];
    const float* f_w2   = (const float*)d_in[9];
    const float* f_b2   = (const float*)d_in[10];
    float* out = (float*)d_out;

    char* ws = (char*)d_ws;
    float* u    = (float*)(ws + 0);          // 64*64*256*4 = 4 MB
    float* v    = (float*)(ws + 4194304);    // 4 MB
    short* w2f  = (short*)(ws + 8388608);    // 128 KB
    float* part = (float*)(ws + 8519680);    // 512*256*4 = 512 KB

    k12_front<<<288, 256, 0, stream>>>(image, conv_w, conv_b, g_w1, g_b1, g_w2,
                                       u, v, w2f);
    k3_pairs<<<512, 256, 0, stream>>>(u, v, w2f, g_b2, part);
    k5_head<<<64, 256, 0, stream>>>(part, f_w1, f_b1, f_w2, f_b2, out);
}

// Round 8
// 66.391 us; speedup vs baseline: 1.2578x; 1.2578x over previous
//
#include <hip/hip_runtime.h>
#include <hip/hip_bf16.h>
#include <stdint.h>

// RNDiscriminator: B=64, d^2=64 positions, 26 features, g: 52->256->256, f: 256->1
// h1[i,j] = relu(u'[j] + v[i]); dominant cost sum_ij relu(h1 @ W2 + b2) = 34.4 GF bf16.
//
// k3: Bf[8][4] W2 fragments resident in regs (static indices only -- rule #20).
// h1 double-buffered (2x32KB LDS), b128 staging (8 writes/thread, fixed swizzle).
// ANTI-PHASE STAGGER: odd half of grid runs MFMA(0-3) -> STAGE -> MFMA(4-7) so
// the two co-resident blocks per CU (blk, blk+256) stop phase-locking their
// stage/MFMA windows. b = blk&63 keeps u-tile sharers on one XCD (L2 reuse).

typedef float f32x4 __attribute__((ext_vector_type(4)));
typedef float f32x2 __attribute__((ext_vector_type(2)));
typedef short short8 __attribute__((ext_vector_type(8)));
typedef int   int4v  __attribute__((ext_vector_type(4)));

__device__ __forceinline__ uint32_t cvt_pk_bf16(float lo, float hi) {
    uint32_t r;
    asm("v_cvt_pk_bf16_f32 %0, %1, %2" : "=v"(r) : "v"(lo), "v"(hi));
    return r;
}
__device__ __forceinline__ f32x2 relu2(f32x2 a) {
    f32x2 z = (f32x2){0.f, 0.f};
    return __builtin_elementwise_max(a, z);
}

// K12: blocks 0..255: fused conv(8x8/s8)+relu+coords -> u,v rows.
//      blocks 256..287: pre-fragment W2 (bf16, fragment-major).
__global__ void k12_front(const float* __restrict__ img, const float* __restrict__ cw,
                          const float* __restrict__ cb, const float* __restrict__ w1,
                          const float* __restrict__ b1, const float* __restrict__ w2,
                          float* __restrict__ u, float* __restrict__ v,
                          short* __restrict__ w2f) {
    int g = blockIdx.x;
    int t = threadIdx.x;
    if (g >= 256) {
        int fi = (g - 256) * 4 + (t >> 6);
        int l = t & 63;
        int ks = fi >> 4, ni2 = fi & 15;
        int n  = ni2 * 16 + (l & 15);
        int k0 = ks * 32 + (l >> 4) * 8;
        float f[8];
        #pragma unroll
        for (int e = 0; e < 8; ++e) f[e] = w2[(k0 + e) * 256 + n];
        union { short8 s; uint32_t w[4]; } A;
        A.w[0] = cvt_pk_bf16(f[0], f[1]);
        A.w[1] = cvt_pk_bf16(f[2], f[3]);
        A.w[2] = cvt_pk_bf16(f[4], f[5]);
        A.w[3] = cvt_pk_bf16(f[6], f[7]);
        *(short8*)(w2f + (fi * 64 + l) * 8) = A.s;
        return;
    }
    __shared__ float xs[16][26];
    int b = g >> 2, q = g & 3, p0 = q * 16;

    for (int idx = t; idx < 416; idx += 256) {
        int pl = idx / 26;
        int ch = idx - pl * 26;
        int pos = p0 + pl;
        int r = pos >> 3, c = pos & 7;
        float val;
        if (ch < 24) {
            float s = cb[ch];
            #pragma unroll
            for (int ci = 0; ci < 3; ++ci)
                #pragma unroll
                for (int kr = 0; kr < 8; ++kr) {
                    const float* ip = img + ((b * 3 + ci) * 64 + r * 8 + kr) * 64 + c * 8;
                    const float* wp = cw + ((ch * 3 + ci) * 8 + kr) * 8;
                    #pragma unroll
                    for (int kc = 0; kc < 8; ++kc) s += ip[kc] * wp[kc];
                }
            val = fmaxf(s, 0.f);
        } else if (ch == 24) {
            val = -1.f + (2.f / 7.f) * (float)c;
        } else {
            val = -1.f + (2.f / 7.f) * (float)r;
        }
        xs[pl][ch] = val;
    }
    __syncthreads();

    // phase 2, k-outer (w1 loads hoisted: 52 loads/thread instead of 832)
    int c = t;
    float bc = b1[c];
    float su[16], sv[16];
    #pragma unroll
    for (int r = 0; r < 16; ++r) { su[r] = bc; sv[r] = 0.f; }
    #pragma unroll 2
    for (int k = 0; k < 26; ++k) {
        float wu = w1[k * 256 + c];
        float wv2 = w1[(26 + k) * 256 + c];
        #pragma unroll
        for (int r = 0; r < 16; ++r) {
            float xv = xs[r][k];
            su[r] += xv * wu;
            sv[r] += xv * wv2;
        }
    }
    #pragma unroll
    for (int r = 0; r < 16; ++r) {
        int bj = b * 64 + p0 + r;
        u[bj * 256 + c] = su[r];
        v[bj * 256 + c] = sv[r];
    }
}

// ---- k3 macros ----
// Staging thread (col16 = t&31, rowbase = t>>5); pass p covers row p*8+rowbase,
// bf16 cols col16*8..+8 -> one ds_write_b128 at byte
// row*512 + (col16*16 ^ (rowbase<<4))   [rowbase = row&7].
#define STAGE_ALL(VSROW, WB)                                           \
{                                                                      \
    f32x4 va = *(const f32x4*)&vs[VSROW][col16 * 8];                   \
    f32x4 vb = *(const f32x4*)&vs[VSROW][col16 * 8 + 4];               \
    _Pragma("unroll 4")                                                \
    for (int p = 0; p < 8; ++p) {                                      \
        f32x4 x0 = *(const f32x4*)(uth + p * 2048);                    \
        f32x4 x1 = *(const f32x4*)(uth + p * 2048 + 4);                \
        f32x2 a0 = relu2((f32x2){x0.x, x0.y} + (f32x2){va.x, va.y});   \
        f32x2 a1 = relu2((f32x2){x0.z, x0.w} + (f32x2){va.z, va.w});   \
        f32x2 a2 = relu2((f32x2){x1.x, x1.y} + (f32x2){vb.x, vb.y});   \
        f32x2 a3 = relu2((f32x2){x1.z, x1.w} + (f32x2){vb.z, vb.w});   \
        int4v d;                                                       \
        d.x = (int)cvt_pk_bf16(a0.x, a0.y);                            \
        d.y = (int)cvt_pk_bf16(a1.x, a1.y);                            \
        d.z = (int)cvt_pk_bf16(a2.x, a2.y);                            \
        d.w = (int)cvt_pk_bf16(a3.x, a3.y);                            \
        *(int4v*)((WB) + p * 4096) = d;                                \
    }                                                                  \
}

// Read: A-frag (row = mi*16+lr, k0 = ks*32+lg*8) at byte
// mi*8192 + lr*512 + (ks>>1)*128 + (xb or xb^64), xb = (lg*16)^((lr&7)<<4).
#define MFMA_ROW(AV, MI, KS)                                                                    \
      acc[MI][0] = __builtin_amdgcn_mfma_f32_16x16x32_bf16(AV, Bf[KS][0], acc[MI][0], 0, 0, 0); \
      acc[MI][1] = __builtin_amdgcn_mfma_f32_16x16x32_bf16(AV, Bf[KS][1], acc[MI][1], 0, 0, 0); \
      acc[MI][2] = __builtin_amdgcn_mfma_f32_16x16x32_bf16(AV, Bf[KS][2], acc[MI][2], 0, 0, 0); \
      acc[MI][3] = __builtin_amdgcn_mfma_f32_16x16x32_bf16(AV, Bf[KS][3], acc[MI][3], 0, 0, 0);

#define MFMA_KS(KS)                                                   \
    { const char* hx = ((KS) & 1) ? hO : hE;                          \
      short8 a0 = *(const short8*)(hx + ((KS) >> 1) * 128);           \
      short8 a1 = *(const short8*)(hx + 8192  + ((KS) >> 1) * 128);   \
      short8 a2 = *(const short8*)(hx + 16384 + ((KS) >> 1) * 128);   \
      short8 a3 = *(const short8*)(hx + 24576 + ((KS) >> 1) * 128);   \
      MFMA_ROW(a0, 0, KS) MFMA_ROW(a1, 1, KS)                         \
      MFMA_ROW(a2, 2, KS) MFMA_ROW(a3, 3, KS) }

__global__ __launch_bounds__(256, 2) void k3_pairs(
        const float* __restrict__ u, const float* __restrict__ v,
        const short* __restrict__ w2f, const float* __restrict__ b2,
        float* __restrict__ part) {
    __shared__ short h1s[2][64 * 256];   // 2 x 32 KB
    __shared__ float vs[8][256];         // 8 KB
    int t = threadIdx.x;
    int lane = t & 63, wv = t >> 6;
    int lr = lane & 15, lg = lane >> 4;
    int blk = blockIdx.x;                 // 0..511
    int b = blk & 63, i0 = (blk >> 6) * 8;
    bool late = (blk >> 8) & 1;           // co-resident pair (blk, blk+256) differ

    // stage the 8 v-rows once
    {
        int q = t >> 5, c8 = (t & 31) * 8;
        const float* vr = v + (b * 64 + i0 + q) * 256 + c8;
        *(float4*)&vs[q][c8]     = *(const float4*)vr;
        *(float4*)&vs[q][c8 + 4] = *(const float4*)(vr + 4);
    }

    // resident B fragments (static indices only)
    short8 Bf[8][4];
    #pragma unroll
    for (int ks = 0; ks < 8; ++ks)
        #pragma unroll
        for (int cg = 0; cg < 4; ++cg)
            Bf[ks][cg] = *(const short8*)(w2f + ((ks * 16 + wv * 4 + cg) * 64 + lane) * 8);

    f32x2 bias2[4];
    #pragma unroll
    for (int cg = 0; cg < 4; ++cg) {
        float bv = b2[wv * 64 + cg * 16 + lr];
        bias2[cg] = (f32x2){bv, bv};
    }

    // staging / read geometry
    int col16 = t & 31, rowbase = t >> 5;
    const float* uth = u + (b * 64 + rowbase) * 256 + col16 * 8;
    int wbase = rowbase * 512 + ((col16 * 16) ^ (rowbase << 4));
    int xb = (lg * 16) ^ ((lr & 7) << 4);
    int rE = lr * 512 + xb;
    int rO = lr * 512 + (xb ^ 64);

    __syncthreads();            // vs ready
    STAGE_ALL(0, (char*)h1s[0] + wbase)
    __syncthreads();            // buf0 ready

    f32x2 csum2[4];
    #pragma unroll
    for (int cg = 0; cg < 4; ++cg) csum2[cg] = (f32x2){0.f, 0.f};

    #pragma unroll 1
    for (int qq = 0; qq < 8; ++qq) {
        const char* hE = (const char*)h1s[qq & 1] + rE;
        const char* hO = (const char*)h1s[qq & 1] + rO;
        char* wb = (char*)h1s[(qq & 1) ^ 1] + wbase;

        f32x4 acc[4][4];
        #pragma unroll
        for (int mi = 0; mi < 4; ++mi)
            #pragma unroll
            for (int cg = 0; cg < 4; ++cg) acc[mi][cg] = (f32x4){0.f, 0.f, 0.f, 0.f};

        if (!late) {
            if (qq < 7) STAGE_ALL(qq + 1, wb)
            __builtin_amdgcn_s_setprio(1);
            MFMA_KS(0) MFMA_KS(1) MFMA_KS(2) MFMA_KS(3)
            MFMA_KS(4) MFMA_KS(5) MFMA_KS(6) MFMA_KS(7)
            __builtin_amdgcn_s_setprio(0);
        } else {
            __builtin_amdgcn_s_setprio(1);
            MFMA_KS(0) MFMA_KS(1) MFMA_KS(2) MFMA_KS(3)
            __builtin_amdgcn_s_setprio(0);
            if (qq < 7) STAGE_ALL(qq + 1, wb)
            __builtin_amdgcn_s_setprio(1);
            MFMA_KS(4) MFMA_KS(5) MFMA_KS(6) MFMA_KS(7)
            __builtin_amdgcn_s_setprio(0);
        }

        // epilogue: relu(C + b2) partial column-sum (packed)
        #pragma unroll
        for (int cg = 0; cg < 4; ++cg) {
            #pragma unroll
            for (int mi = 0; mi < 4; ++mi) {
                f32x2 lo = relu2((f32x2){acc[mi][cg].x, acc[mi][cg].y} + bias2[cg]);
                f32x2 hi = relu2((f32x2){acc[mi][cg].z, acc[mi][cg].w} + bias2[cg]);
                csum2[cg] = csum2[cg] + lo + hi;
            }
        }
        __syncthreads();
    }

    // flush: reduce over lg groups; lanes 0-15 store
    #pragma unroll
    for (int cg = 0; cg < 4; ++cg) {
        float s = csum2[cg].x + csum2[cg].y;
        s += __shfl_xor(s, 16);
        s += __shfl_xor(s, 32);
        if (lane < 16) part[blk * 256 + wv * 64 + cg * 16 + lr] = s;
    }
}

// K5: pooled[b] = sum of the 8 part rows for b (blk = b + 64*g); then f-head.
__global__ void k5_head(const float* __restrict__ part, const float* __restrict__ fw1,
                        const float* __restrict__ fb1, const float* __restrict__ fw2,
                        const float* __restrict__ fb2, float* __restrict__ out) {
    __shared__ float P[256];
    __shared__ float wsum[4];
    int b = blockIdx.x, t = threadIdx.x;
    float s0 = 0.f;
    #pragma unroll
    for (int g = 0; g < 8; ++g) s0 += part[(b + 64 * g) * 256 + t];
    P[t] = s0;
    __syncthreads();
    float a0 = 0.f, a1 = 0.f, a2 = 0.f, a3 = 0.f;
    for (int k = 0; k < 64; ++k) {
        a0 += P[k]       * fw1[k * 256 + t];
        a1 += P[k + 64]  * fw1[(k + 64) * 256 + t];
        a2 += P[k + 128] * fw1[(k + 128) * 256 + t];
        a3 += P[k + 192] * fw1[(k + 192) * 256 + t];
    }
    float h = fmaxf(fb1[t] + a0 + a1 + a2 + a3, 0.f);
    float p = h * fw2[t];
    #pragma unroll
    for (int off = 32; off >= 1; off >>= 1) p += __shfl_xor(p, off);
    if ((t & 63) == 0) wsum[t >> 6] = p;
    __syncthreads();
    if (t == 0) out[b] = wsum[0] + wsum[1] + wsum[2] + wsum[3] + fb2[0];
}

extern "C" void kernel_launch(void* const* d_in, const int* in_sizes, int n_in,
                              void* d_out, int out_size, void* d_ws, size_t ws_size,
                              hipStream_t stream) {
    const float* image  = (const float*)d_in[0];
    const float* conv_w = (const float*)d_in[1];
    const float* conv_b = (const float*)d_in[2];
    const float* g_w1   = (const float*)d_in[3];
    const float* g_b1   = (const float*)d_in[4];
    const float* g_w2   = (const float*)d_in[5];
    const float* g_b2   = (const float*)d_in[6];
    const float* f_w1   = (const float*)d_in[7];
    const float* f_b1   = (const float*)d_in[8];
    const float* f_w2   = (const float*)d_in[9];
    const float* f_b2   = (const float*)d_in[10];
    float* out = (float*)d_out;

    char* ws = (char*)d_ws;
    float* u    = (float*)(ws + 0);          // 64*64*256*4 = 4 MB
    float* v    = (float*)(ws + 4194304);    // 4 MB
    short* w2f  = (short*)(ws + 8388608);    // 128 KB
    float* part = (float*)(ws + 8519680);    // 512*256*4 = 512 KB

    k12_front<<<288, 256, 0, stream>>>(image, conv_w, conv_b, g_w1, g_b1, g_w2,
                                       u, v, w2f);
    k3_pairs<<<512, 256, 0, stream>>>(u, v, w2f, g_b2, part);
    k5_head<<<64, 256, 0, stream>>>(part, f_w1, f_b1, f_w2, f_b2, out);
}

// Round 9
// 60.109 us; speedup vs baseline: 1.3893x; 1.1045x over previous
//
#include <hip/hip_runtime.h>
#include <hip/hip_bf16.h>
#include <stdint.h>

// RNDiscriminator: B=64, d^2=64 positions, 26 features, g: 52->256->256, f: 256->1
// h1[i,j] = relu(u'[j] + v[i]); dominant cost sum_ij relu(h1 @ W2 + b2) = 34.4 GF bf16.
//
// k3 (R8): 256 blocks x 512 thr (8 waves, 1 block/CU). u-tile RESIDENT IN
// REGISTERS (32 f32/thread) -- staging is pure VALU+ds_write, zero global loads
// in the 16-unit loop. Wave w owns cols w*32..+32: Bf[8][2]=64 VGPR, acc[4][2].
// h1 double-buffered (2x32KB LDS, XOR-swizzled b128). One barrier per unit.

typedef float f32x4 __attribute__((ext_vector_type(4)));
typedef float f32x2 __attribute__((ext_vector_type(2)));
typedef short short8 __attribute__((ext_vector_type(8)));
typedef int   int4v  __attribute__((ext_vector_type(4)));

__device__ __forceinline__ uint32_t cvt_pk_bf16(float lo, float hi) {
    uint32_t r;
    asm("v_cvt_pk_bf16_f32 %0, %1, %2" : "=v"(r) : "v"(lo), "v"(hi));
    return r;
}
__device__ __forceinline__ f32x2 relu2(f32x2 a) {
    f32x2 z = (f32x2){0.f, 0.f};
    return __builtin_elementwise_max(a, z);
}

// K12: blocks 0..255: fused conv(8x8/s8)+relu+coords -> u,v rows.
//      blocks 256..287: pre-fragment W2 (bf16, fragment-major).
__global__ void k12_front(const float* __restrict__ img, const float* __restrict__ cw,
                          const float* __restrict__ cb, const float* __restrict__ w1,
                          const float* __restrict__ b1, const float* __restrict__ w2,
                          float* __restrict__ u, float* __restrict__ v,
                          short* __restrict__ w2f) {
    int g = blockIdx.x;
    int t = threadIdx.x;
    if (g >= 256) {
        int fi = (g - 256) * 4 + (t >> 6);
        int l = t & 63;
        int ks = fi >> 4, ni2 = fi & 15;
        int n  = ni2 * 16 + (l & 15);
        int k0 = ks * 32 + (l >> 4) * 8;
        float f[8];
        #pragma unroll
        for (int e = 0; e < 8; ++e) f[e] = w2[(k0 + e) * 256 + n];
        union { short8 s; uint32_t w[4]; } A;
        A.w[0] = cvt_pk_bf16(f[0], f[1]);
        A.w[1] = cvt_pk_bf16(f[2], f[3]);
        A.w[2] = cvt_pk_bf16(f[4], f[5]);
        A.w[3] = cvt_pk_bf16(f[6], f[7]);
        *(short8*)(w2f + (fi * 64 + l) * 8) = A.s;
        return;
    }
    __shared__ float xs[16][26];
    int b = g >> 2, q = g & 3, p0 = q * 16;

    for (int idx = t; idx < 416; idx += 256) {
        int pl = idx / 26;
        int ch = idx - pl * 26;
        int pos = p0 + pl;
        int r = pos >> 3, c = pos & 7;
        float val;
        if (ch < 24) {
            float s = cb[ch];
            #pragma unroll
            for (int ci = 0; ci < 3; ++ci)
                #pragma unroll
                for (int kr = 0; kr < 8; ++kr) {
                    const float* ip = img + ((b * 3 + ci) * 64 + r * 8 + kr) * 64 + c * 8;
                    const float* wp = cw + ((ch * 3 + ci) * 8 + kr) * 8;
                    #pragma unroll
                    for (int kc = 0; kc < 8; ++kc) s += ip[kc] * wp[kc];
                }
            val = fmaxf(s, 0.f);
        } else if (ch == 24) {
            val = -1.f + (2.f / 7.f) * (float)c;
        } else {
            val = -1.f + (2.f / 7.f) * (float)r;
        }
        xs[pl][ch] = val;
    }
    __syncthreads();

    // phase 2, k-outer (w1 loads hoisted)
    int c = t;
    float bc = b1[c];
    float su[16], sv[16];
    #pragma unroll
    for (int r = 0; r < 16; ++r) { su[r] = bc; sv[r] = 0.f; }
    #pragma unroll 2
    for (int k = 0; k < 26; ++k) {
        float wu = w1[k * 256 + c];
        float wv2 = w1[(26 + k) * 256 + c];
        #pragma unroll
        for (int r = 0; r < 16; ++r) {
            float xv = xs[r][k];
            su[r] += xv * wu;
            sv[r] += xv * wv2;
        }
    }
    #pragma unroll
    for (int r = 0; r < 16; ++r) {
        int bj = b * 64 + p0 + r;
        u[bj * 256 + c] = su[r];
        v[bj * 256 + c] = sv[r];
    }
}

// ---- k3 macros ----
// STAGE(Q, BUF): rows rq*4+rr (rr unrolled), cols col8*8..+8 from u-registers
// + vs[Q]; one ds_write_b128 per row at precomputed swizzled offset wb[rr].
#define STAGE(Q, BUF)                                                  \
{                                                                      \
    f32x4 va = *(const f32x4*)&vs[Q][col8 * 8];                        \
    f32x4 vb = *(const f32x4*)&vs[Q][col8 * 8 + 4];                    \
    _Pragma("unroll")                                                  \
    for (int rr = 0; rr < 4; ++rr) {                                   \
        f32x2 a0 = relu2((f32x2){u0[rr].x, u0[rr].y} + (f32x2){va.x, va.y}); \
        f32x2 a1 = relu2((f32x2){u0[rr].z, u0[rr].w} + (f32x2){va.z, va.w}); \
        f32x2 a2 = relu2((f32x2){u1[rr].x, u1[rr].y} + (f32x2){vb.x, vb.y}); \
        f32x2 a3 = relu2((f32x2){u1[rr].z, u1[rr].w} + (f32x2){vb.z, vb.w}); \
        int4v d;                                                       \
        d.x = (int)cvt_pk_bf16(a0.x, a0.y);                            \
        d.y = (int)cvt_pk_bf16(a1.x, a1.y);                            \
        d.z = (int)cvt_pk_bf16(a2.x, a2.y);                            \
        d.w = (int)cvt_pk_bf16(a3.x, a3.y);                            \
        *(int4v*)((char*)(BUF) + wb[rr]) = d;                          \
    }                                                                  \
}

// A-frag read: (row = mi*16+lr, k0 = ks*32+lg*8) at byte
// mi*8192 + lr*512 + (ks>>1)*128 + (XB or XB^64), XB = (lg*16)^((lr&7)<<4).
#define MFMA_KS(KS)                                                   \
    { const char* hx = ((KS) & 1) ? hO : hE;                          \
      short8 a0 = *(const short8*)(hx + ((KS) >> 1) * 128);           \
      short8 a1 = *(const short8*)(hx + 8192  + ((KS) >> 1) * 128);   \
      short8 a2 = *(const short8*)(hx + 16384 + ((KS) >> 1) * 128);   \
      short8 a3 = *(const short8*)(hx + 24576 + ((KS) >> 1) * 128);   \
      acc[0][0] = __builtin_amdgcn_mfma_f32_16x16x32_bf16(a0, Bf[KS][0], acc[0][0], 0, 0, 0); \
      acc[1][0] = __builtin_amdgcn_mfma_f32_16x16x32_bf16(a1, Bf[KS][0], acc[1][0], 0, 0, 0); \
      acc[2][0] = __builtin_amdgcn_mfma_f32_16x16x32_bf16(a2, Bf[KS][0], acc[2][0], 0, 0, 0); \
      acc[3][0] = __builtin_amdgcn_mfma_f32_16x16x32_bf16(a3, Bf[KS][0], acc[3][0], 0, 0, 0); \
      acc[0][1] = __builtin_amdgcn_mfma_f32_16x16x32_bf16(a0, Bf[KS][1], acc[0][1], 0, 0, 0); \
      acc[1][1] = __builtin_amdgcn_mfma_f32_16x16x32_bf16(a1, Bf[KS][1], acc[1][1], 0, 0, 0); \
      acc[2][1] = __builtin_amdgcn_mfma_f32_16x16x32_bf16(a2, Bf[KS][1], acc[2][1], 0, 0, 0); \
      acc[3][1] = __builtin_amdgcn_mfma_f32_16x16x32_bf16(a3, Bf[KS][1], acc[3][1], 0, 0, 0); }

__global__ __launch_bounds__(512, 2) void k3_pairs(
        const float* __restrict__ u, const float* __restrict__ v,
        const short* __restrict__ w2f, const float* __restrict__ b2,
        float* __restrict__ part) {
    __shared__ short h1s[2][64 * 256];   // 64 KB
    __shared__ float vs[16][256];        // 16 KB
    int t = threadIdx.x;
    int lane = t & 63, wv = t >> 6;      // wv 0..7
    int lr = lane & 15, lg = lane >> 4;
    int blk = blockIdx.x;                // 0..255
    int b = blk & 63, i0 = (blk >> 6) * 16;

    // stage the 16 v rows once (vs[q][c]), 8 floats/thread
    {
        int q = t >> 5, c8 = (t & 31) * 8;
        const float* vr = v + (b * 64 + i0 + q) * 256 + c8;
        *(float4*)&vs[q][c8]     = *(const float4*)vr;
        *(float4*)&vs[q][c8 + 4] = *(const float4*)(vr + 4);
    }

    // resident B fragments: wave wv covers cols wv*32 .. +32
    short8 Bf[8][2];
    #pragma unroll
    for (int ks = 0; ks < 8; ++ks)
        #pragma unroll
        for (int cg = 0; cg < 2; ++cg)
            Bf[ks][cg] = *(const short8*)(w2f + ((ks * 16 + wv * 2 + cg) * 64 + lane) * 8);

    f32x2 bias2[2];
    #pragma unroll
    for (int cg = 0; cg < 2; ++cg) {
        float bv = b2[wv * 32 + cg * 16 + lr];
        bias2[cg] = (f32x2){bv, bv};
    }

    // u residency: thread (col8 = t&31, rq = t>>5) holds rows rq*4..+4,
    // cols col8*8..+8 as f32 (32 VGPR)
    int col8 = t & 31, rq = t >> 5;
    const float* up = u + (b * 64 + rq * 4) * 256 + col8 * 8;
    f32x4 u0[4], u1[4];
    int wb[4];
    #pragma unroll
    for (int rr = 0; rr < 4; ++rr) {
        u0[rr] = *(const f32x4*)(up + rr * 256);
        u1[rr] = *(const f32x4*)(up + rr * 256 + 4);
        int row = rq * 4 + rr;
        wb[rr] = row * 512 + ((col8 * 16) ^ ((row & 7) << 4));
    }

    // read geometry
    int XB = (lg * 16) ^ ((lr & 7) << 4);
    int rE = lr * 512 + XB;
    int rO = lr * 512 + (XB ^ 64);

    __syncthreads();            // vs ready
    STAGE(0, h1s[0])
    __syncthreads();            // buf0 ready

    f32x2 csum2[2];
    csum2[0] = (f32x2){0.f, 0.f};
    csum2[1] = (f32x2){0.f, 0.f};

    #pragma unroll 1
    for (int q = 0; q < 16; ++q) {
        if (q < 15) STAGE(q + 1, h1s[(q + 1) & 1])

        const char* hE = (const char*)h1s[q & 1] + rE;
        const char* hO = (const char*)h1s[q & 1] + rO;

        f32x4 acc[4][2];
        #pragma unroll
        for (int mi = 0; mi < 4; ++mi)
            #pragma unroll
            for (int cg = 0; cg < 2; ++cg) acc[mi][cg] = (f32x4){0.f, 0.f, 0.f, 0.f};

        __builtin_amdgcn_s_setprio(1);
        MFMA_KS(0) MFMA_KS(1) MFMA_KS(2) MFMA_KS(3)
        MFMA_KS(4) MFMA_KS(5) MFMA_KS(6) MFMA_KS(7)
        __builtin_amdgcn_s_setprio(0);

        // epilogue: relu(C + b2) partial column-sum (packed)
        #pragma unroll
        for (int cg = 0; cg < 2; ++cg) {
            #pragma unroll
            for (int mi = 0; mi < 4; ++mi) {
                f32x2 lo = relu2((f32x2){acc[mi][cg].x, acc[mi][cg].y} + bias2[cg]);
                f32x2 hi = relu2((f32x2){acc[mi][cg].z, acc[mi][cg].w} + bias2[cg]);
                csum2[cg] = csum2[cg] + lo + hi;
            }
        }
        __syncthreads();
    }

    // flush: reduce over lg groups; lanes 0-15 store
    #pragma unroll
    for (int cg = 0; cg < 2; ++cg) {
        float s = csum2[cg].x + csum2[cg].y;
        s += __shfl_xor(s, 16);
        s += __shfl_xor(s, 32);
        if (lane < 16) part[blk * 256 + wv * 32 + cg * 16 + lr] = s;
    }
}

// K5: pooled[b] = sum of the 4 part rows for b (blk = b + 64*g); then f-head.
__global__ void k5_head(const float* __restrict__ part, const float* __restrict__ fw1,
                        const float* __restrict__ fb1, const float* __restrict__ fw2,
                        const float* __restrict__ fb2, float* __restrict__ out) {
    __shared__ float P[256];
    __shared__ float wsum[4];
    int b = blockIdx.x, t = threadIdx.x;
    float s0 = 0.f;
    #pragma unroll
    for (int g = 0; g < 4; ++g) s0 += part[(b + 64 * g) * 256 + t];
    P[t] = s0;
    __syncthreads();
    float a0 = 0.f, a1 = 0.f, a2 = 0.f, a3 = 0.f;
    for (int k = 0; k < 64; ++k) {
        a0 += P[k]       * fw1[k * 256 + t];
        a1 += P[k + 64]  * fw1[(k + 64) * 256 + t];
        a2 += P[k + 128] * fw1[(k + 128) * 256 + t];
        a3 += P[k + 192] * fw1[(k + 192) * 256 + t];
    }
    float h = fmaxf(fb1[t] + a0 + a1 + a2 + a3, 0.f);
    float p = h * fw2[t];
    #pragma unroll
    for (int off = 32; off >= 1; off >>= 1) p += __shfl_xor(p, off);
    if ((t & 63) == 0) wsum[t >> 6] = p;
    __syncthreads();
    if (t == 0) out[b] = wsum[0] + wsum[1] + wsum[2] + wsum[3] + fb2[0];
}

extern "C" void kernel_launch(void* const* d_in, const int* in_sizes, int n_in,
                              void* d_out, int out_size, void* d_ws, size_t ws_size,
                              hipStream_t stream) {
    const float* image  = (const float*)d_in[0];
    const float* conv_w = (const float*)d_in[1];
    const float* conv_b = (const float*)d_in[2];
    const float* g_w1   = (const float*)d_in[3];
    const float* g_b1   = (const float*)d_in[4];
    const float* g_w2   = (const float*)d_in[5];
    const float* g_b2   = (const float*)d_in[6];
    const float* f_w1   = (const float*)d_in[7];
    const float* f_b1   = (const float*)d_in[8];
    const float* f_w2   = (const float*)d_in[9];
    const float* f_b2   = (const float*)d_in[10];
    float* out = (float*)d_out;

    char* ws = (char*)d_ws;
    float* u    = (float*)(ws + 0);          // 64*64*256*4 = 4 MB
    float* v    = (float*)(ws + 4194304);    // 4 MB
    short* w2f  = (short*)(ws + 8388608);    // 128 KB
    float* part = (float*)(ws + 8519680);    // 256*256*4 = 256 KB

    k12_front<<<288, 256, 0, stream>>>(image, conv_w, conv_b, g_w1, g_b1, g_w2,
                                       u, v, w2f);
    k3_pairs<<<256, 512, 0, stream>>>(u, v, w2f, g_b2, part);
    k5_head<<<64, 256, 0, stream>>>(part, f_w1, f_b1, f_w2, f_b2, out);
}